// Round 1
// 498.267 us; speedup vs baseline: 1.0697x; 1.0697x over previous
//
#include <hip/hip_runtime.h>

// Problem constants: N=64 batch, C=23 chromosomes, G=20000 genes, H=64 hidden.
// x:(N,G,H) f32, chrom_mat:(C,G) one-hot f32, attention:(C,H) f32. out:(N,C,H) f32.
#define N_ 64
#define C_ 23
#define G_ 20000
#define H_ 64

// 16-lane rotate-add allreduce step via DPP (row_ror) — pure VALU, no LDS pipe.
// CTRL: 0x120|n = row_ror:n (rotation within each 16-lane row).
template <int CTRL>
__device__ __forceinline__ float ror_add(float v) {
    int r = __builtin_amdgcn_update_dpp(0, __float_as_int(v), CTRL, 0xf, 0xf, true);
    return v + __int_as_float(r);
}

// ---------------------------------------------------------------------------
// Kernel 1: fused assign + scatter. Fixed-capacity buckets (capacity G_ per
// chromosome — safe for any assignment) make the exclusive-scan kernel and the
// assign[] array unnecessary: one dispatch instead of three.
__global__ void bucket_kernel(const float* __restrict__ chrom,
                              int* __restrict__ counts,   // C_, zeroed
                              int* __restrict__ bucket) { // C_*G_
    int g = blockIdx.x * blockDim.x + threadIdx.x;
    if (g >= G_) return;
    int c_found = 0;
    #pragma unroll
    for (int c = 0; c < C_; ++c) {
        if (chrom[c * G_ + g] != 0.f) c_found = c;
    }
    int pos = atomicAdd(&counts[c_found], 1);
    bucket[c_found * G_ + pos] = g;
}

// ---------------------------------------------------------------------------
// Kernel 2 (main): one block per (n,c) — the block owns the WHOLE chromosome,
// so it can normalize and write the output directly: no global atomics, no
// acc/denom workspace, no finalize kernel, no big memset.
// 16-lane gene groups: lane sub holds h=4*sub..4*sub+3; dot reduced with 4 DPP
// rotate-adds (pure VALU — rounds 2/3 of the prior session proved in-loop LDS
// ops serialize everything).
__global__ __launch_bounds__(256) void main_pass(
    const float* __restrict__ x,        // (N,G,H)
    const float* __restrict__ attn,     // (C,H)
    const int* __restrict__ counts,     // C_
    const int* __restrict__ bucket,     // C_*G_
    float* __restrict__ out)            // (N,C,H)
{
    int b = blockIdx.x;
    int c = b % C_;
    int n = b / C_;

    int cnt = counts[c];
    const int* __restrict__ bk = bucket + c * G_;

    int tid  = threadIdx.x;
    int sub  = tid & 15;   // lane in 16-lane gene group: h = 4*sub..4*sub+3
    int gid  = tid >> 4;   // gene group id within block, 0..15
    int wave = tid >> 6;   // 0..3

    const float4 a4 = ((const float4*)(attn + c * H_))[sub];

    float4 accv = make_float4(0.f, 0.f, 0.f, 0.f);
    float dsum = 0.f;

    const float* xb = x + (size_t)n * G_ * H_;

    // unroll 4: batches the (L1-resident) index loads ahead of the dependent
    // 256B x gathers — 4 KB in flight per wave, well past the latency product.
    #pragma unroll 4
    for (int p = gid; p < cnt; p += 16) {
        int g = bk[p];
        const float4 x4 = ((const float4*)(xb + (size_t)g * H_))[sub];
        float part = fmaf(a4.x, x4.x, fmaf(a4.y, x4.y, fmaf(a4.z, x4.z, a4.w * x4.w)));
        // 16-lane allreduce: rotate-add by 8,4,2,1 (row_ror DPP).
        part = ror_add<0x128>(part);
        part = ror_add<0x124>(part);
        part = ror_add<0x122>(part);
        part = ror_add<0x121>(part);
        float w = 0.f;
        if (part != 0.f) {          // mask = (att != 0), matches reference
            float lr = (part >= 0.f) ? part : 0.2f * part;
            w = __expf(lr);
        }
        accv.x = fmaf(w, x4.x, accv.x);
        accv.y = fmaf(w, x4.y, accv.y);
        accv.z = fmaf(w, x4.z, accv.z);
        accv.w = fmaf(w, x4.w, accv.w);
        dsum += w;                  // identical across the 16 lanes of a group
    }

    // Reduce across the 4 gene-groups within each wave.
    #pragma unroll
    for (int m = 16; m <= 32; m <<= 1) {
        accv.x += __shfl_xor(accv.x, m);
        accv.y += __shfl_xor(accv.y, m);
        accv.z += __shfl_xor(accv.z, m);
        accv.w += __shfl_xor(accv.w, m);
        dsum   += __shfl_xor(dsum, m);
    }

    // Cross-wave reduce (epilogue-only LDS, one barrier) + normalize + store.
    __shared__ float4 pacc[4][16];
    __shared__ float  pd[4];
    int lane = tid & 63;
    if (lane < 16) {
        pacc[wave][lane] = accv;
        if (lane == 0) pd[wave] = dsum;
    }
    __syncthreads();
    if (tid < 16) {
        float4 s0 = pacc[0][tid], s1 = pacc[1][tid], s2 = pacc[2][tid], s3 = pacc[3][tid];
        float d = fmaxf(pd[0] + pd[1] + pd[2] + pd[3], 1e-10f);
        float4 o;
        o.x = (s0.x + s1.x + s2.x + s3.x) / d;
        o.y = (s0.y + s1.y + s2.y + s3.y) / d;
        o.z = (s0.z + s1.z + s2.z + s3.z) / d;
        o.w = (s0.w + s1.w + s2.w + s3.w) / d;
        ((float4*)(out + ((size_t)(n * C_ + c)) * H_))[tid] = o;
    }
}

// ---------------------------------------------------------------------------
extern "C" void kernel_launch(void* const* d_in, const int* in_sizes, int n_in,
                              void* d_out, int out_size, void* d_ws, size_t ws_size,
                              hipStream_t stream) {
    const float* x     = (const float*)d_in[0];   // N*G*H
    const float* chrom = (const float*)d_in[1];   // C*G
    const float* attn  = (const float*)d_in[2];   // C*H
    float* out = (float*)d_out;

    // Workspace layout (everything we read is rewritten every call — safe
    // under harness re-poisoning):
    //   counts : C_    ints  (zeroed here)
    //   bucket : C_*G_ ints  (entries [0,counts[c]) written before read)
    int* counts = (int*)d_ws;
    int* bucket = counts + C_;

    hipMemsetAsync(counts, 0, C_ * sizeof(int), stream);

    int gb = (G_ + 255) / 256;
    bucket_kernel<<<gb, 256, 0, stream>>>(chrom, counts, bucket);

    main_pass<<<N_ * C_, 256, 0, stream>>>(x, attn, counts, bucket, out);
}

// Round 2
// 454.508 us; speedup vs baseline: 1.1726x; 1.0963x over previous
//
#include <hip/hip_runtime.h>

// Problem constants: N=64 batch, C=23 chromosomes, G=20000 genes, H=64 hidden.
// x:(N,G,H) f32, chrom_mat:(C,G) one-hot f32, attention:(C,H) f32. out:(N,C,H) f32.
#define N_ 64
#define C_ 23
#define G_ 20000
#define H_ 64

// 16-lane rotate-add allreduce step via DPP (row_ror) — pure VALU, no LDS pipe.
// CTRL: 0x120|n = row_ror:n (rotation within each 16-lane row).
template <int CTRL>
__device__ __forceinline__ float ror_add(float v) {
    int r = __builtin_amdgcn_update_dpp(0, __float_as_int(v), CTRL, 0xf, 0xf, true);
    return v + __int_as_float(r);
}

// ---------------------------------------------------------------------------
// Kernel 1: fused assign + scatter, two-level reservation.
// R1 issued 20000 global atomicAdds onto 23 consecutive ints (2 cache lines)
// — a serialized L2 atomic chain. Here: LDS-local rank (fast, ~11 collisions
// per counter), then ONE global atomicAdd per (block, chromosome) to reserve
// a contiguous range (79*23 = 1817 global atomics, 11x fewer), then bulk
// scatter. Bucket-internal gene order changes — irrelevant, main_pass only
// sums over the bucket.
__global__ __launch_bounds__(256) void bucket_kernel(
    const float* __restrict__ chrom,
    int* __restrict__ counts,   // C_, zeroed
    int* __restrict__ bucket) { // C_*G_
    __shared__ int lcnt[C_];
    __shared__ int lbase[C_];
    int tid = threadIdx.x;
    if (tid < C_) lcnt[tid] = 0;
    __syncthreads();

    int g = blockIdx.x * blockDim.x + tid;
    int c_found = 0;
    int r = 0;
    bool valid = (g < G_);
    if (valid) {
        #pragma unroll
        for (int c = 0; c < C_; ++c) {
            if (chrom[c * G_ + g] != 0.f) c_found = c;
        }
        r = atomicAdd(&lcnt[c_found], 1);   // local rank within (block, c)
    }
    __syncthreads();
    if (tid < C_) {
        int n = lcnt[tid];
        lbase[tid] = n ? atomicAdd(&counts[tid], n) : 0;  // range reservation
    }
    __syncthreads();
    if (valid) bucket[c_found * G_ + lbase[c_found] + r] = g;
}

// ---------------------------------------------------------------------------
// Kernel 2 (main): one block per (n,c) — the block owns the WHOLE chromosome,
// so it can normalize and write the output directly: no global atomics, no
// acc/denom workspace, no finalize kernel, no big memset.
// 16-lane gene groups: lane sub holds h=4*sub..4*sub+3; dot reduced with 4 DPP
// rotate-adds (pure VALU — prior session proved in-loop LDS ops serialize).
// UNCHANGED from R1 to isolate the bucket_kernel delta.
__global__ __launch_bounds__(256) void main_pass(
    const float* __restrict__ x,        // (N,G,H)
    const float* __restrict__ attn,     // (C,H)
    const int* __restrict__ counts,     // C_
    const int* __restrict__ bucket,     // C_*G_
    float* __restrict__ out)            // (N,C,H)
{
    int b = blockIdx.x;
    int c = b % C_;
    int n = b / C_;

    int cnt = counts[c];
    const int* __restrict__ bk = bucket + c * G_;

    int tid  = threadIdx.x;
    int sub  = tid & 15;   // lane in 16-lane gene group: h = 4*sub..4*sub+3
    int gid  = tid >> 4;   // gene group id within block, 0..15
    int wave = tid >> 6;   // 0..3

    const float4 a4 = ((const float4*)(attn + c * H_))[sub];

    float4 accv = make_float4(0.f, 0.f, 0.f, 0.f);
    float dsum = 0.f;

    const float* xb = x + (size_t)n * G_ * H_;

    // unroll 4: batches the (L2-resident) index loads ahead of the dependent
    // 256B x gathers — 4 KB in flight per wave, well past the latency product.
    #pragma unroll 4
    for (int p = gid; p < cnt; p += 16) {
        int g = bk[p];
        const float4 x4 = ((const float4*)(xb + (size_t)g * H_))[sub];
        float part = fmaf(a4.x, x4.x, fmaf(a4.y, x4.y, fmaf(a4.z, x4.z, a4.w * x4.w)));
        // 16-lane allreduce: rotate-add by 8,4,2,1 (row_ror DPP).
        part = ror_add<0x128>(part);
        part = ror_add<0x124>(part);
        part = ror_add<0x122>(part);
        part = ror_add<0x121>(part);
        float w = 0.f;
        if (part != 0.f) {          // mask = (att != 0), matches reference
            float lr = (part >= 0.f) ? part : 0.2f * part;
            w = __expf(lr);
        }
        accv.x = fmaf(w, x4.x, accv.x);
        accv.y = fmaf(w, x4.y, accv.y);
        accv.z = fmaf(w, x4.z, accv.z);
        accv.w = fmaf(w, x4.w, accv.w);
        dsum += w;                  // identical across the 16 lanes of a group
    }

    // Reduce across the 4 gene-groups within each wave.
    #pragma unroll
    for (int m = 16; m <= 32; m <<= 1) {
        accv.x += __shfl_xor(accv.x, m);
        accv.y += __shfl_xor(accv.y, m);
        accv.z += __shfl_xor(accv.z, m);
        accv.w += __shfl_xor(accv.w, m);
        dsum   += __shfl_xor(dsum, m);
    }

    // Cross-wave reduce (epilogue-only LDS, one barrier) + normalize + store.
    __shared__ float4 pacc[4][16];
    __shared__ float  pd[4];
    int lane = tid & 63;
    if (lane < 16) {
        pacc[wave][lane] = accv;
        if (lane == 0) pd[wave] = dsum;
    }
    __syncthreads();
    if (tid < 16) {
        float4 s0 = pacc[0][tid], s1 = pacc[1][tid], s2 = pacc[2][tid], s3 = pacc[3][tid];
        float d = fmaxf(pd[0] + pd[1] + pd[2] + pd[3], 1e-10f);
        float4 o;
        o.x = (s0.x + s1.x + s2.x + s3.x) / d;
        o.y = (s0.y + s1.y + s2.y + s3.y) / d;
        o.z = (s0.z + s1.z + s2.z + s3.z) / d;
        o.w = (s0.w + s1.w + s2.w + s3.w) / d;
        ((float4*)(out + ((size_t)(n * C_ + c)) * H_))[tid] = o;
    }
}

// ---------------------------------------------------------------------------
extern "C" void kernel_launch(void* const* d_in, const int* in_sizes, int n_in,
                              void* d_out, int out_size, void* d_ws, size_t ws_size,
                              hipStream_t stream) {
    const float* x     = (const float*)d_in[0];   // N*G*H
    const float* chrom = (const float*)d_in[1];   // C*G
    const float* attn  = (const float*)d_in[2];   // C*H
    float* out = (float*)d_out;

    // Workspace layout (everything we read is rewritten every call — safe
    // under harness re-poisoning):
    //   counts : C_    ints  (zeroed here)
    //   bucket : C_*G_ ints  (entries [0,counts[c]) written before read)
    int* counts = (int*)d_ws;
    int* bucket = counts + C_;

    hipMemsetAsync(counts, 0, C_ * sizeof(int), stream);

    int gb = (G_ + 255) / 256;
    bucket_kernel<<<gb, 256, 0, stream>>>(chrom, counts, bucket);

    main_pass<<<N_ * C_, 256, 0, stream>>>(x, attn, counts, bucket, out);
}